// Round 16
// baseline (9839.709 us; speedup 1.0000x reference)
//
#include <hip/hip_runtime.h>
#include <hip/hip_fp16.h>

// GRU 2-layer, B=256 S=1024 F=75 H=256.
// Round 16: R11's exchange schedule (proven), scaled to 4 members/group:
//  64 blocks (16 groups x 4 members of 64 units), 1024 threads (16 waves),
//  2 gate-tile chains per wave (32 chains = 4 ut x 8 tiles). Weights hoisted
//  from GLOBAL via blocking asm loads into VGPRs (opaque: no remat, no
//  in-flight hazard). LDS = hcat/xs/ctile/red only (~57KB). Exchange protocol,
//  slots/tags/parity, issue/validate points, 4-barrier structure: R11 verbatim
//  (scaled thread maps: 512-thread halves, 8 u32 gather per thread).

#define NS 1024
#define NF 75
#define NH 256

#define W0S 360   // halves: 96(x pad) + 256(h) + 8 pad
#define W1S 512   // 256(h0) + 256(h1)
#define HCS 520   // hcat row halves: [h0 0..255 | h1 256..511] + pad
#define XSS 104   // 96 + 8 pad

#define W0_HALVES (48 * W0S)                 // 17280
#define W1_HALVES (48 * W1S)                 // 24576
#define IMG_HALVES (W0_HALVES + W1_HALVES)   // 41856

// d_ws layout (bytes)
#define WIMG_OFF 0
#define WIMG_BYTES (16 * IMG_HALVES * 2)     // 1,339,392
#define HX0_OFF WIMG_BYTES
#define HX_WORDS (2 * 16 * 16 * 256)         // 131072 u32 (2 parities)
#define HX1_OFF (HX0_OFF + HX_WORDS * 4)
#define HX_TOTAL_BYTES (2 * HX_WORDS * 4)    // 1 MiB

typedef _Float16 f16x8 __attribute__((ext_vector_type(8)));
typedef float f32x4 __attribute__((ext_vector_type(4)));
typedef unsigned int u32x4 __attribute__((ext_vector_type(4)));

#define PINV(x) asm volatile("" : "+v"(x))

__device__ __forceinline__ void bar_lds() {
  asm volatile("s_waitcnt lgkmcnt(0)" ::: "memory");
  __builtin_amdgcn_s_barrier();
  __builtin_amdgcn_sched_barrier(0);
}

// blocking opaque global load of one f16x8 fragment (weight hoist)
__device__ __forceinline__ f16x8 ldg8(const _Float16* p) {
  f16x8 v;
  asm volatile("global_load_dwordx4 %0, %1, off\n\ts_waitcnt vmcnt(0)"
               : "=v"(v) : "v"(p) : "memory");
  return v;
}

// MALL-routed coherent ops (sc0 sc1), placement-independent (R4..R11-proven)
__device__ __forceinline__ void st_u32_sys(unsigned* p, unsigned v) {
  asm volatile("global_store_dword %0, %1, off sc0 sc1" :: "v"(p), "v"(v) : "memory");
}
__device__ __forceinline__ void issue2_sys(const unsigned* p, u32x4& a, u32x4& b) {
  asm volatile(
      "global_load_dwordx4 %0, %2, off sc0 sc1\n\t"
      "global_load_dwordx4 %1, %2, off offset:16 sc0 sc1"
      : "=&v"(a), "=&v"(b) : "v"(p) : "memory");
}
__device__ __forceinline__ void ld2b_sys(const unsigned* p, u32x4& a, u32x4& b) {
  asm volatile(
      "global_load_dwordx4 %0, %2, off sc0 sc1\n\t"
      "global_load_dwordx4 %1, %2, off offset:16 sc0 sc1\n\t"
      "s_waitcnt vmcnt(0)"
      : "=&v"(a), "=&v"(b) : "v"(p) : "memory");
}

__device__ __forceinline__ bool tags_ok2(const u32x4& a, const u32x4& b, unsigned tg) {
  u32x4 m4 = __builtin_elementwise_min(a, b);
  unsigned m = m4.x;
  m = m4.y < m ? m4.y : m;
  m = m4.z < m ? m4.z : m;
  m = m4.w < m ? m4.w : m;
  return (m >> 16) == tg;
}

__device__ __forceinline__ void unpack8(_Float16* d, const u32x4& a, const u32x4& b) {
  u32x4 w;
  w.x = (a.x & 0xffffu) | (a.y << 16);
  w.y = (a.z & 0xffffu) | (a.w << 16);
  w.z = (b.x & 0xffffu) | (b.y << 16);
  w.w = (b.z & 0xffffu) | (b.w << 16);
  *(u32x4*)d = w;
}

// Weight image per 16-unit slice s (halves): W0 [48][W0S] (x cols 0..74 @0,
// h cols @96..351), W1 [48][512] (h0 cols 0..255, h1 cols 256..511);
// row = gate*16+u (gate 0:r 1:z 2:n).
__global__ void prep_wimg(const float* __restrict__ wih0, const float* __restrict__ whh0,
                          const float* __restrict__ wih1, const float* __restrict__ whh1,
                          _Float16* __restrict__ wimg) {
  const int total = 16 * IMG_HALVES;
  for (int i = blockIdx.x * blockDim.x + threadIdx.x; i < total;
       i += gridDim.x * blockDim.x) {
    const int j = i / IMG_HALVES;
    int rem = i - j * IMG_HALVES;
    float val = 0.f;
    if (rem < W0_HALVES) {
      const int row = rem / W0S, k = rem - row * W0S;
      const int gate = row >> 4, u = row & 15;
      const int grow = gate * NH + j * 16 + u;
      if (k < NF) val = wih0[grow * NF + k];
      else if (k >= 96 && k < 352) val = whh0[grow * NH + (k - 96)];
    } else {
      rem -= W0_HALVES;
      const int row = rem >> 9, k = rem & 511;
      const int gate = row >> 4, u = row & 15;
      const int grow = gate * NH + j * 16 + u;
      if (k < 256) val = wih1[grow * NH + k];
      else         val = whh1[grow * NH + (k - 256)];
    }
    wimg[i] = (_Float16)val;
  }
}

__global__ __launch_bounds__(1024, 1) void gru_mfma(
    const float* __restrict__ x,
    const float* __restrict__ b_ih0, const float* __restrict__ b_hh0,
    const float* __restrict__ b_ih1, const float* __restrict__ b_hh1,
    const float* __restrict__ w_lin, const float* __restrict__ b_lin,
    const _Float16* __restrict__ wimg,
    unsigned* __restrict__ hx0, unsigned* __restrict__ hx1,
    float* __restrict__ out)
{
  const int tid = threadIdx.x;
  const int bid = blockIdx.x;
  const int gr = bid >> 2;             // group 0..15 (rows gr*16..+15)
  const int j  = bid & 3;              // member 0..3 (units j*64..+63)

  __shared__ _Float16 hcat[16 * HCS];        // 16640 B
  __shared__ _Float16 xs[2 * 16 * XSS];      // 6656 B
  __shared__ float    ct[32][64][4];         // 32768 B
  __shared__ float    red[16][17];           // 1088 B

  int dead = 0, spins = 0;

  const int wid = tid >> 6, lane = tid & 63;
  const int lrow = lane & 15, lko = (lane >> 4) * 8;
  const bool half0 = (tid < 512);
  const int t5 = tid & 511;
  const int row2 = t5 >> 5;                  // gate-set row 0..15
  const int upair = (t5 & 31) * 2;           // local units upair, upair+1
  const int ut = upair >> 4;                 // local ut 0..3 (same for both)
  const int gu0 = j * 64 + upair;
  const int chunk5 = gr * 4096 + t5 * 8;     // gather: 8 u32 per thread
  const int li0 = ((row2 >> 2) << 4) | (upair & 15), rg = row2 & 3;

  // biases for this thread's two gate-sets
  float br_[2], bz_[2], bnx_[2], bnh_[2];
  #pragma unroll
  for (int e = 0; e < 2; ++e) {
    const int g = gu0 + e;
    if (half0) {
      br_[e]  = b_ih0[g] + b_hh0[g];
      bz_[e]  = b_ih0[NH + g] + b_hh0[NH + g];
      bnx_[e] = b_ih0[2 * NH + g];
      bnh_[e] = b_hh0[2 * NH + g];
    } else {
      br_[e]  = b_ih1[g] + b_hh1[g];
      bz_[e]  = b_ih1[NH + g] + b_hh1[NH + g];
      bnx_[e] = b_ih1[2 * NH + g];
      bnh_[e] = b_hh1[2 * NH + g];
    }
  }

  // ---- weight hoist: blocking opaque loads from global (no LDS staging) ----
  f16x8 Bp[32];
  int cid0, cid1;
  if (wid < 8) {
    const int lut = wid >> 1;
    const _Float16* W0 = wimg + (size_t)(j * 4 + lut) * IMG_HALVES;
    if (!(wid & 1)) {                        // L0 r,z (11 each)
      cid0 = 4 * lut + 0; cid1 = 4 * lut + 1;
      const _Float16* br2 = W0 + lrow * W0S;
      const _Float16* bz2 = W0 + (16 + lrow) * W0S;
      #pragma unroll
      for (int kb = 0; kb < 3; ++kb) { Bp[kb]      = ldg8(br2 + kb * 32 + lko); }
      #pragma unroll
      for (int kb = 0; kb < 8; ++kb) { Bp[3 + kb]  = ldg8(br2 + 96 + kb * 32 + lko); }
      #pragma unroll
      for (int kb = 0; kb < 3; ++kb) { Bp[11 + kb] = ldg8(bz2 + kb * 32 + lko); }
      #pragma unroll
      for (int kb = 0; kb < 8; ++kb) { Bp[14 + kb] = ldg8(bz2 + 96 + kb * 32 + lko); }
    } else {                                 // L0 nx (3), nh (8)
      cid0 = 4 * lut + 2; cid1 = 4 * lut + 3;
      const _Float16* bn2 = W0 + (32 + lrow) * W0S;
      #pragma unroll
      for (int kb = 0; kb < 3; ++kb) { Bp[kb]     = ldg8(bn2 + kb * 32 + lko); }
      #pragma unroll
      for (int kb = 0; kb < 8; ++kb) { Bp[3 + kb] = ldg8(bn2 + 96 + kb * 32 + lko); }
    }
  } else {
    const int lut = (wid - 8) >> 1;
    const _Float16* W1 = wimg + (size_t)(j * 4 + lut) * IMG_HALVES + W0_HALVES;
    if (!(wid & 1)) {                        // L1 r,z (16 each)
      cid0 = 16 + 4 * lut + 0; cid1 = 16 + 4 * lut + 1;
      const _Float16* br2 = W1 + lrow * W1S;
      const _Float16* bz2 = W1 + (16 + lrow) * W1S;
      #pragma unroll
      for (int kb = 0; kb < 16; ++kb) { Bp[kb]      = ldg8(br2 + kb * 32 + lko); }
      #pragma unroll
      for (int kb = 0; kb < 16; ++kb) { Bp[16 + kb] = ldg8(bz2 + kb * 32 + lko); }
    } else {                                 // L1 nx (kb0..7=h0), nh (kb8..15=h1)
      cid0 = 16 + 4 * lut + 2; cid1 = 16 + 4 * lut + 3;
      const _Float16* bn2 = W1 + (32 + lrow) * W1S;
      #pragma unroll
      for (int kb = 0; kb < 16; ++kb) { Bp[kb] = ldg8(bn2 + kb * 32 + lko); }
    }
  }
  #pragma unroll
  for (int i = 0; i < 32; ++i) PINV(Bp[i]);

  // ---- init LDS state ----
  for (int i = tid; i < 16 * HCS; i += 1024) hcat[i] = (_Float16)0.f;
  for (int i = tid; i < 2 * 16 * XSS; i += 1024) xs[i] = (_Float16)0.f;

  const int xr0 = tid / NF, xc0 = tid - xr0 * NF;            // tid < 1200 always
  const bool xv1 = (tid < 176);
  const int i1 = 1024 + tid;
  const int xr1 = i1 / NF, xc1 = i1 - xr1 * NF;
  const float* __restrict__ xbase = x + (size_t)(gr * 16) * NS * NF;
  if (tid < 1200) xs[xr0 * XSS + xc0] = (_Float16)xbase[(size_t)xr0 * NS * NF + xc0];
  if (xv1)        xs[xr1 * XSS + xc1] = (_Float16)xbase[(size_t)xr1 * NS * NF + xc1];

  float h0f[2] = {0.f, 0.f}, h1f[2] = {0.f, 0.f};
  __syncthreads();   // init done

  for (int p = 0; p <= NS; ++p) {
    const int par = p & 1;

    // (1) x[p+1] prefetch
    float xf0 = 0.f, xf1 = 0.f;
    if (p + 1 < NS) {
      if (tid < 1200) xf0 = xbase[((size_t)xr0 * NS + (p + 1)) * NF + xc0];
      if (xv1)        xf1 = xbase[((size_t)xr1 * NS + (p + 1)) * NF + xc1];
    }

    // (a) half1: async h1[p-2] gather (slot (p-2)&1 = par, tag p-1)
    u32x4 G0, G1;
    if (!half0 && p >= 2)
      issue2_sys(hx1 + par * 65536 + chunk5, G0, G1);

    // (2)+(3) pre-S1 MFMA
    {
      const _Float16* __restrict__ xp = xs + par * (16 * XSS) + lrow * XSS + lko;
      const _Float16* __restrict__ hp = hcat + lrow * HCS + lko;
      f32x4 aR = {0.f, 0.f, 0.f, 0.f}, aZ = {0.f, 0.f, 0.f, 0.f};
      if (wid < 8) {
        if (!(wid & 1)) {                    // L0 r,z — full chains
          f16x8 xa[3];
          #pragma unroll
          for (int kb = 0; kb < 3; ++kb) xa[kb] = *(const f16x8*)(xp + kb * 32);
          f16x8 hf[8];
          #pragma unroll
          for (int kb = 0; kb < 8; ++kb) hf[kb] = *(const f16x8*)(hp + kb * 32);
          #pragma unroll
          for (int kb = 0; kb < 3; ++kb)
            aR = __builtin_amdgcn_mfma_f32_16x16x32_f16(xa[kb], Bp[kb], aR, 0, 0, 0);
          #pragma unroll
          for (int kb = 0; kb < 8; ++kb)
            aR = __builtin_amdgcn_mfma_f32_16x16x32_f16(hf[kb], Bp[3 + kb], aR, 0, 0, 0);
          #pragma unroll
          for (int kb = 0; kb < 3; ++kb)
            aZ = __builtin_amdgcn_mfma_f32_16x16x32_f16(xa[kb], Bp[11 + kb], aZ, 0, 0, 0);
          #pragma unroll
          for (int kb = 0; kb < 8; ++kb)
            aZ = __builtin_amdgcn_mfma_f32_16x16x32_f16(hf[kb], Bp[14 + kb], aZ, 0, 0, 0);
          *(f32x4*)&ct[cid0][lane][0] = aR;
          *(f32x4*)&ct[cid1][lane][0] = aZ;
        } else {                             // L0 nx, nh — full chains
          f16x8 xa[3];
          #pragma unroll
          for (int kb = 0; kb < 3; ++kb) xa[kb] = *(const f16x8*)(xp + kb * 32);
          f16x8 hf[8];
          #pragma unroll
          for (int kb = 0; kb < 8; ++kb) hf[kb] = *(const f16x8*)(hp + kb * 32);
          #pragma unroll
          for (int kb = 0; kb < 3; ++kb)
            aR = __builtin_amdgcn_mfma_f32_16x16x32_f16(xa[kb], Bp[kb], aR, 0, 0, 0);
          #pragma unroll
          for (int kb = 0; kb < 8; ++kb)
            aZ = __builtin_amdgcn_mfma_f32_16x16x32_f16(hf[kb], Bp[3 + kb], aZ, 0, 0, 0);
          *(f32x4*)&ct[cid0][lane][0] = aR;
          *(f32x4*)&ct[cid1][lane][0] = aZ;
        }
      } else {
        if (!(wid & 1)) {                    // L1 r,z — h0 halves (carried)
          f16x8 hf[8];
          #pragma unroll
          for (int kb = 0; kb < 8; ++kb) hf[kb] = *(const f16x8*)(hp + kb * 32);
          #pragma unroll
          for (int kb = 0; kb < 8; ++kb)
            aR = __builtin_amdgcn_mfma_f32_16x16x32_f16(hf[kb], Bp[kb], aR, 0, 0, 0);
          #pragma unroll
          for (int kb = 0; kb < 8; ++kb)
            aZ = __builtin_amdgcn_mfma_f32_16x16x32_f16(hf[kb], Bp[16 + kb], aZ, 0, 0, 0);
        } else {                             // L1 nx — full (h0)
          f16x8 hf[8];
          #pragma unroll
          for (int kb = 0; kb < 8; ++kb) hf[kb] = *(const f16x8*)(hp + kb * 32);
          #pragma unroll
          for (int kb = 0; kb < 8; ++kb)
            aR = __builtin_amdgcn_mfma_f32_16x16x32_f16(hf[kb], Bp[kb], aR, 0, 0, 0);
          *(f32x4*)&ct[cid0][lane][0] = aR;
        }
      }

      // (3.5) stage x[p+1]
      if (p + 1 < NS) {
        if (tid < 1200) xs[((p + 1) & 1) * (16 * XSS) + xr0 * XSS + xc0] = (_Float16)xf0;
        if (xv1)        xs[((p + 1) & 1) * (16 * XSS) + xr1 * XSS + xc1] = (_Float16)xf1;
      }
      bar_lds();   // S1

      // (4) CONCURRENT: half0 = L0 gates + publish h0[p]; half1 = validate h1[p-2]
      if (half0) {
        if (p < NS) {
          #pragma unroll
          for (int e = 0; e < 2; ++e) {
            const int li = li0 + e;
            const float ar = ct[4 * ut + 0][li][rg] + br_[e];
            const float az = ct[4 * ut + 1][li][rg] + bz_[e];
            const float nx = ct[4 * ut + 2][li][rg] + bnx_[e];
            const float nh = ct[4 * ut + 3][li][rg] + bnh_[e];
            const float r = 1.f / (1.f + __expf(-ar));
            const float z = 1.f / (1.f + __expf(-az));
            const float n = tanhf(nx + r * nh);
            h0f[e] = (1.f - z) * n + z * h0f[e];
            union { _Float16 h; unsigned short s; } c; c.h = (_Float16)h0f[e];
            st_u32_sys(hx0 + par * 65536 + gr * 4096 + row2 * 256 + gu0 + e,
                       (unsigned)c.s | ((unsigned)(p + 1) << 16));
          }
        }
      } else {
        if (p >= 2) {
          asm volatile("s_waitcnt vmcnt(0)" : "+v"(G0), "+v"(G1) :: "memory");
          while (!tags_ok2(G0, G1, (unsigned)(p - 1))) {
            if (++spins > 200000) { dead = 1; break; }
            __builtin_amdgcn_s_sleep(1);
            ld2b_sys(hx1 + par * 65536 + chunk5, G0, G1);
          }
          unpack8(hcat + row2 * HCS + 256 + (t5 & 31) * 8 + ((row2 * 0)), G0, G1);
        }
      }
      bar_lds();   // S2

      // (6) half0: async h0[p] gather; L1 waves: h1-part MFMAs
      u32x4 A0, A1;
      if (half0 && p < NS)
        issue2_sys(hx0 + par * 65536 + chunk5, A0, A1);
      if (wid >= 8) {
        const _Float16* __restrict__ hq = hcat + lrow * HCS + 256 + lko;
        f16x8 hg[8];
        #pragma unroll
        for (int kb = 0; kb < 8; ++kb) hg[kb] = *(const f16x8*)(hq + kb * 32);
        if (!(wid & 1)) {                    // finish L1 r,z
          #pragma unroll
          for (int kb = 0; kb < 8; ++kb)
            aR = __builtin_amdgcn_mfma_f32_16x16x32_f16(hg[kb], Bp[8 + kb], aR, 0, 0, 0);
          #pragma unroll
          for (int kb = 0; kb < 8; ++kb)
            aZ = __builtin_amdgcn_mfma_f32_16x16x32_f16(hg[kb], Bp[24 + kb], aZ, 0, 0, 0);
          *(f32x4*)&ct[cid0][lane][0] = aR;
          *(f32x4*)&ct[cid1][lane][0] = aZ;
        } else {                             // L1 nh — full (h1)
          f32x4 a = {0.f, 0.f, 0.f, 0.f};
          #pragma unroll
          for (int kb = 0; kb < 8; ++kb)
            a = __builtin_amdgcn_mfma_f32_16x16x32_f16(hg[kb], Bp[8 + kb], a, 0, 0, 0);
          *(f32x4*)&ct[cid1][lane][0] = a;
        }
      }
      bar_lds();   // S3

      // (7)/(8) CONCURRENT: half1 = L1 gates + publish h1[p-1]; half0 = validate h0[p]
      if (!half0) {
        if (p >= 1) {
          #pragma unroll
          for (int e = 0; e < 2; ++e) {
            const int li = li0 + e;
            const float ar = ct[16 + 4 * ut + 0][li][rg] + br_[e];
            const float az = ct[16 + 4 * ut + 1][li][rg] + bz_[e];
            const float nx = ct[16 + 4 * ut + 2][li][rg] + bnx_[e];
            const float nh = ct[16 + 4 * ut + 3][li][rg] + bnh_[e];
            const float r = 1.f / (1.f + __expf(-ar));
            const float z = 1.f / (1.f + __expf(-az));
            const float n = tanhf(nx + r * nh);
            h1f[e] = (1.f - z) * n + z * h1f[e];
            union { _Float16 h; unsigned short s; } c; c.h = (_Float16)h1f[e];
            st_u32_sys(hx1 + ((p - 1) & 1) * 65536 + gr * 4096 + row2 * 256 + gu0 + e,
                       (unsigned)c.s | ((unsigned)p << 16));
          }
        }
      } else {
        if (p < NS) {
          asm volatile("s_waitcnt vmcnt(0)" : "+v"(A0), "+v"(A1) :: "memory");
          while (!tags_ok2(A0, A1, (unsigned)(p + 1))) {
            if (++spins > 200000) { dead = 1; break; }
            __builtin_amdgcn_s_sleep(1);
            ld2b_sys(hx0 + par * 65536 + chunk5, A0, A1);
          }
          unpack8(hcat + row2 * HCS + (t5 & 31) * 8, A0, A1);
        }
      }
      bar_lds();   // S4
    }
  }

  // ---- tail: half1 blocking-gathers h1[NS-1] (slot (NS-1)&1, tag NS) ----
  if (!half0) {
    u32x4 C0, C1;
    const unsigned* src = hx1 + ((NS - 1) & 1) * 65536 + chunk5;
    for (;;) {
      ld2b_sys(src, C0, C1);
      if (tags_ok2(C0, C1, (unsigned)NS)) break;
      if (++spins > 200000) { dead = 1; break; }
      __builtin_amdgcn_s_sleep(1);
    }
    unpack8(hcat + row2 * HCS + 256 + (t5 & 31) * 8, C0, C1);
  }
  __syncthreads();
  if (tid < 256) {
    const int rr = tid >> 4, uu = tid & 15;
    float part = 0.f;
    #pragma unroll
    for (int e = 0; e < 16; ++e)
      part += (float)hcat[rr * HCS + 256 + uu * 16 + e] * w_lin[uu * 16 + e];
    red[rr][uu] = part;
  }
  __syncthreads();
  if (j == 0 && tid < 16) {
    float s = 0.f;
    #pragma unroll
    for (int e = 0; e < 16; ++e) s += red[tid][e];
    out[gr * 16 + tid] = s + b_lin[0];
  }
}

extern "C" void kernel_launch(void* const* d_in, const int* in_sizes, int n_in,
                              void* d_out, int out_size, void* d_ws, size_t ws_size,
                              hipStream_t stream) {
  (void)in_sizes; (void)n_in; (void)out_size; (void)ws_size;
  const float* x     = (const float*)d_in[0];
  const float* w_ih0 = (const float*)d_in[1];
  const float* w_hh0 = (const float*)d_in[2];
  const float* b_ih0 = (const float*)d_in[3];
  const float* b_hh0 = (const float*)d_in[4];
  const float* w_ih1 = (const float*)d_in[5];
  const float* w_hh1 = (const float*)d_in[6];
  const float* b_ih1 = (const float*)d_in[7];
  const float* b_hh1 = (const float*)d_in[8];
  const float* w_lin = (const float*)d_in[9];
  const float* b_lin = (const float*)d_in[10];

  char* ws = (char*)d_ws;
  _Float16* wimg = (_Float16*)(ws + WIMG_OFF);
  unsigned* hx0  = (unsigned*)(ws + HX0_OFF);
  unsigned* hx1  = (unsigned*)(ws + HX1_OFF);

  hipMemsetAsync(ws + HX0_OFF, 0, HX_TOTAL_BYTES, stream);
  prep_wimg<<<1024, 256, 0, stream>>>(w_ih0, w_hh0, w_ih1, w_hh1, wimg);
  gru_mfma<<<64, 1024, 0, stream>>>(x, b_ih0, b_hh0, b_ih1, b_hh1,
                                    w_lin, b_lin, wimg, hx0, hx1,
                                    (float*)d_out);
}

// Round 17
// 2507.756 us; speedup vs baseline: 3.9237x; 3.9237x over previous
//
#include <hip/hip_runtime.h>
#include <hip/hip_fp16.h>

// GRU 2-layer, B=256 S=1024 F=75 H=256.
// FINAL (= Round 11, proven 2373us): 8 waves/block (512 thr) = 2 waves/SIMD.
//  One MFMA tile per wave. Role-split halves run concurrently: tid<256 owns h0
//  (L0 gates + publish + validate h0[p]); tid>=256 owns h1 (validate h1[p-2] +
//  L1 gates + publish). Tagged MALL exchange (sc0 sc1), parity double-buffer,
//  tag-equality validation, per-launch memset, dead-latch bailout.

#define NS 1024
#define NF 75
#define NH 256

#define W0S 360   // halves: 96(x pad) + 256(h) + 8 pad
#define W1S 520   // 256(h0) + 256(h1) + 8 pad
#define HCS 520   // hcat row halves: [h0 0..255 | h1 256..511] + pad
#define XSS 104   // 96 + 8 pad

#define W0_HALVES (48 * W0S)                 // 17280
#define W1_HALVES (48 * W1S)                 // 24960
#define IMG_HALVES (W0_HALVES + W1_HALVES)   // 42240 halves = 84480 B

// shared aliasing offsets (bytes)
#define HCAT_OFF 0
#define XS_OFF   16640
#define CT_OFF   23296
#define RED_OFF  31488

// d_ws layout (bytes)
#define WIMG_OFF 0
#define WIMG_BYTES (16 * IMG_HALVES * 2)
#define HX0_OFF WIMG_BYTES
#define HX_WORDS (2 * 16 * 16 * 256)
#define HX1_OFF (HX0_OFF + HX_WORDS * 4)
#define HX_TOTAL_BYTES (2 * HX_WORDS * 4)    // 1 MiB

typedef _Float16 f16x8 __attribute__((ext_vector_type(8)));
typedef float f32x4 __attribute__((ext_vector_type(4)));
typedef unsigned int u32x4 __attribute__((ext_vector_type(4)));

#define PINV(x) asm volatile("" : "+v"(x))

__device__ __forceinline__ void bar_lds() {
  asm volatile("s_waitcnt lgkmcnt(0)" ::: "memory");
  __builtin_amdgcn_s_barrier();
  __builtin_amdgcn_sched_barrier(0);
}

// MALL-routed coherent ops (sc0 sc1), placement-independent
__device__ __forceinline__ void st_u32_sys(unsigned* p, unsigned v) {
  asm volatile("global_store_dword %0, %1, off sc0 sc1" :: "v"(p), "v"(v) : "memory");
}
__device__ __forceinline__ void issue4_sys(const unsigned* p, u32x4& a, u32x4& b,
                                           u32x4& c, u32x4& d) {
  asm volatile(
      "global_load_dwordx4 %0, %4, off sc0 sc1\n\t"
      "global_load_dwordx4 %1, %4, off offset:16 sc0 sc1\n\t"
      "global_load_dwordx4 %2, %4, off offset:32 sc0 sc1\n\t"
      "global_load_dwordx4 %3, %4, off offset:48 sc0 sc1"
      : "=&v"(a), "=&v"(b), "=&v"(c), "=&v"(d) : "v"(p) : "memory");
}
__device__ __forceinline__ void ld4b_sys(const unsigned* p, u32x4& a, u32x4& b,
                                         u32x4& c, u32x4& d) {
  asm volatile(
      "global_load_dwordx4 %0, %4, off sc0 sc1\n\t"
      "global_load_dwordx4 %1, %4, off offset:16 sc0 sc1\n\t"
      "global_load_dwordx4 %2, %4, off offset:32 sc0 sc1\n\t"
      "global_load_dwordx4 %3, %4, off offset:48 sc0 sc1\n\t"
      "s_waitcnt vmcnt(0)"
      : "=&v"(a), "=&v"(b), "=&v"(c), "=&v"(d) : "v"(p) : "memory");
}

__device__ __forceinline__ bool tags_ok(const u32x4& a, const u32x4& b,
                                        const u32x4& c, const u32x4& e, unsigned tg) {
  u32x4 m4 = __builtin_elementwise_min(__builtin_elementwise_min(a, b),
                                       __builtin_elementwise_min(c, e));
  unsigned m = m4.x;
  m = m4.y < m ? m4.y : m;
  m = m4.z < m ? m4.z : m;
  m = m4.w < m ? m4.w : m;
  return (m >> 16) == tg;
}

__device__ __forceinline__ void unpack16(_Float16* d, const u32x4& a, const u32x4& b,
                                         const u32x4& c, const u32x4& e) {
  u32x4 w0 = { (a.x & 0xffffu) | (a.y << 16), (a.z & 0xffffu) | (a.w << 16),
               (b.x & 0xffffu) | (b.y << 16), (b.z & 0xffffu) | (b.w << 16) };
  u32x4 w1 = { (c.x & 0xffffu) | (c.y << 16), (c.z & 0xffffu) | (c.w << 16),
               (e.x & 0xffffu) | (e.y << 16), (e.z & 0xffffu) | (e.w << 16) };
  *(u32x4*)d = w0;
  *(u32x4*)(d + 8) = w1;
}

// Weight image per block j (halves): W0 [48][W0S] (x cols 0..74, h cols 96..351),
// W1 [48][W1S] (h0 cols 0..255, h1 cols 256..511); row = gate*16+u.
__global__ void prep_wimg(const float* __restrict__ wih0, const float* __restrict__ whh0,
                          const float* __restrict__ wih1, const float* __restrict__ whh1,
                          _Float16* __restrict__ wimg) {
  const int total = 16 * IMG_HALVES;
  for (int i = blockIdx.x * blockDim.x + threadIdx.x; i < total;
       i += gridDim.x * blockDim.x) {
    const int j = i / IMG_HALVES;
    int rem = i - j * IMG_HALVES;
    float val = 0.f;
    if (rem < W0_HALVES) {
      const int row = rem / W0S, k = rem - row * W0S;
      const int gate = row >> 4, u = row & 15;
      const int grow = gate * NH + j * 16 + u;
      if (k < NF) val = wih0[grow * NF + k];
      else if (k >= 96 && k < 352) val = whh0[grow * NH + (k - 96)];
    } else {
      rem -= W0_HALVES;
      const int row = rem / W1S, k = rem - row * W1S;
      const int gate = row >> 4, u = row & 15;
      const int grow = gate * NH + j * 16 + u;
      if (k < 256) val = wih1[grow * NH + k];
      else if (k < 512) val = whh1[grow * NH + (k - 256)];
    }
    wimg[i] = (_Float16)val;
  }
}

__global__ __launch_bounds__(512, 1) void gru_mfma(
    const float* __restrict__ x,
    const float* __restrict__ b_ih0, const float* __restrict__ b_hh0,
    const float* __restrict__ b_ih1, const float* __restrict__ b_hh1,
    const float* __restrict__ w_lin, const float* __restrict__ b_lin,
    const _Float16* __restrict__ wimg,
    unsigned* __restrict__ hx0, unsigned* __restrict__ hx1,
    float* __restrict__ out)
{
  const int tid = threadIdx.x;
  const int bid = blockIdx.x;
  const int gr = (bid & 7) + ((bid >> 7) << 3);
  const int j  = (bid >> 3) & 15;

  __shared__ f16x8 smem8[IMG_HALVES / 8];
  _Float16* Wst  = (_Float16*)smem8;
  _Float16* hcat = (_Float16*)((char*)smem8 + HCAT_OFF);
  _Float16* xs   = (_Float16*)((char*)smem8 + XS_OFF);
  float (*ctile)[64][4] = (float(*)[64][4])((char*)smem8 + CT_OFF);
  float (*red)[17]      = (float(*)[17])((char*)smem8 + RED_OFF);

  int dead = 0, spins = 0;

  // ---- stage weight image ----
  {
    const float4* src = (const float4*)(wimg + (size_t)j * IMG_HALVES);
    float4* dst = (float4*)Wst;
    for (int i = tid; i < IMG_HALVES / 8; i += 512) dst[i] = src[i];
  }

  const int t8 = tid & 255;
  const int row = t8 >> 4, u = t8 & 15, gu = j * 16 + u;
  const int wid = tid >> 6, lane = tid & 63;
  const int lrow = lane & 15, lko = (lane >> 4) * 8;
  const int chunk = gr * 4096 + row * 256 + u * 16;

  float gbr, gbz, gbnx, gbnh;
  if (tid < 256) {
    gbr  = b_ih0[gu] + b_hh0[gu];
    gbz  = b_ih0[NH + gu] + b_hh0[NH + gu];
    gbnx = b_ih0[2 * NH + gu];
    gbnh = b_hh0[2 * NH + gu];
  } else {
    gbr  = b_ih1[gu] + b_hh1[gu];
    gbz  = b_ih1[NH + gu] + b_hh1[NH + gu];
    gbnx = b_ih1[2 * NH + gu];
    gbnh = b_hh1[2 * NH + gu];
  }

  __syncthreads();   // Sa: weights staged

  // ---- hoist per-wave B-fragments (one tile per wave) ----
  _Float16* W0s = Wst;
  _Float16* W1s = Wst + W0_HALVES;
  f16x8 Bf[16];
  if (wid == 0) {            // ct0 = L0-r
    const _Float16* wb = W0s + lrow * W0S + lko;
    #pragma unroll
    for (int i = 0; i < 11; ++i) { Bf[i] = *(const f16x8*)(wb + i * 32); PINV(Bf[i]); }
  } else if (wid == 1) {     // ct1 = L0-z
    const _Float16* wb = W0s + (16 + lrow) * W0S + lko;
    #pragma unroll
    for (int i = 0; i < 11; ++i) { Bf[i] = *(const f16x8*)(wb + i * 32); PINV(Bf[i]); }
  } else if (wid == 2) {     // ct2 = L0-nx (x-part only)
    const _Float16* wb = W0s + (32 + lrow) * W0S + lko;
    #pragma unroll
    for (int i = 0; i < 3; ++i) { Bf[i] = *(const f16x8*)(wb + i * 32); PINV(Bf[i]); }
  } else if (wid == 3) {     // ct3 = L0-nh (h-part)
    const _Float16* wb = W0s + (32 + lrow) * W0S + lko;
    #pragma unroll
    for (int i = 0; i < 8; ++i) { Bf[i] = *(const f16x8*)(wb + (3 + i) * 32); PINV(Bf[i]); }
  } else if (wid == 4) {     // ct4 = L1-r (h0 cols then h1 cols)
    const _Float16* wn = W1s + lrow * W1S + lko;
    #pragma unroll
    for (int i = 0; i < 16; ++i) { Bf[i] = *(const f16x8*)(wn + i * 32); PINV(Bf[i]); }
  } else if (wid == 5) {     // ct5 = L1-z
    const _Float16* wn = W1s + (16 + lrow) * W1S + lko;
    #pragma unroll
    for (int i = 0; i < 16; ++i) { Bf[i] = *(const f16x8*)(wn + i * 32); PINV(Bf[i]); }
  } else if (wid == 6) {     // ct6 = L1-nx (h0 cols)
    const _Float16* wn = W1s + (32 + lrow) * W1S + lko;
    #pragma unroll
    for (int i = 0; i < 8; ++i) { Bf[i] = *(const f16x8*)(wn + i * 32); PINV(Bf[i]); }
  } else {                   // ct7 = L1-nh (h1 cols)
    const _Float16* wn = W1s + (32 + lrow) * W1S + lko;
    #pragma unroll
    for (int i = 0; i < 8; ++i) { Bf[i] = *(const f16x8*)(wn + (8 + i) * 32); PINV(Bf[i]); }
  }
  __syncthreads();   // Sb: hoist done, weight bytes may be clobbered

  for (int i = tid; i < 16 * HCS; i += 512) hcat[i] = (_Float16)0.f;
  for (int i = tid; i < 2 * 16 * XSS; i += 512) xs[i] = (_Float16)0.f;

  int xr_[3], xc_[3]; bool xv_[3];
  #pragma unroll
  for (int i = 0; i < 3; ++i) {
    const int idx = i * 512 + tid;
    xv_[i] = idx < 16 * NF;
    xr_[i] = xv_[i] ? idx / NF : 0;
    xc_[i] = xv_[i] ? idx % NF : 0;
  }
  const float* __restrict__ xbase = x + (size_t)(gr * 16) * NS * NF;
  #pragma unroll
  for (int i = 0; i < 3; ++i)
    if (xv_[i]) xs[xr_[i] * XSS + xc_[i]] =
        (_Float16)xbase[(size_t)xr_[i] * NS * NF + xc_[i]];

  float h0f = 0.f, h1f = 0.f;
  __syncthreads();   // Sc

  for (int p = 0; p <= NS; ++p) {
    const int par = p & 1;

    // (1) x prefetch
    float xf[3];
    if (p + 1 < NS) {
      #pragma unroll
      for (int i = 0; i < 3; ++i)
        if (xv_[i]) xf[i] = xbase[((size_t)xr_[i] * NS + (p + 1)) * NF + xc_[i]];
    }

    // (a) half1: async h1[p-2] gather (published a full phase ago)
    u32x4 G0, G1, G2, G3;
    if (tid >= 256 && p >= 2)
      issue4_sys(hx1 + par * 65536 + chunk, G0, G1, G2, G3);

    // (2)+(3) per-wave A-fragments + pre-barrier MFMAs
    const _Float16* __restrict__ xp = xs + par * (16 * XSS) + lrow * XSS + lko;
    const _Float16* __restrict__ hp = hcat + lrow * HCS + lko;
    f32x4 acc45 = {0.f, 0.f, 0.f, 0.f};   // wid4/5 carried across S2
    if (wid <= 1) {
      f16x8 xa0 = *(const f16x8*)(xp);
      f16x8 xa1 = *(const f16x8*)(xp + 32);
      f16x8 xa2 = *(const f16x8*)(xp + 64);
      f16x8 hfr[8];
      #pragma unroll
      for (int kb = 0; kb < 8; ++kb) hfr[kb] = *(const f16x8*)(hp + kb * 32);
      f32x4 a = {0.f, 0.f, 0.f, 0.f};
      a = __builtin_amdgcn_mfma_f32_16x16x32_f16(xa0, Bf[0], a, 0, 0, 0);
      a = __builtin_amdgcn_mfma_f32_16x16x32_f16(xa1, Bf[1], a, 0, 0, 0);
      a = __builtin_amdgcn_mfma_f32_16x16x32_f16(xa2, Bf[2], a, 0, 0, 0);
      #pragma unroll
      for (int kb = 0; kb < 8; ++kb)
        a = __builtin_amdgcn_mfma_f32_16x16x32_f16(hfr[kb], Bf[3 + kb], a, 0, 0, 0);
      *(f32x4*)&ctile[wid][lane][0] = a;
    } else if (wid == 2) {
      f16x8 xa0 = *(const f16x8*)(xp);
      f16x8 xa1 = *(const f16x8*)(xp + 32);
      f16x8 xa2 = *(const f16x8*)(xp + 64);
      f32x4 a = {0.f, 0.f, 0.f, 0.f};
      a = __builtin_amdgcn_mfma_f32_16x16x32_f16(xa0, Bf[0], a, 0, 0, 0);
      a = __builtin_amdgcn_mfma_f32_16x16x32_f16(xa1, Bf[1], a, 0, 0, 0);
      a = __builtin_amdgcn_mfma_f32_16x16x32_f16(xa2, Bf[2], a, 0, 0, 0);
      *(f32x4*)&ctile[2][lane][0] = a;
    } else if (wid == 3) {
      f16x8 hfr[8];
      #pragma unroll
      for (int kb = 0; kb < 8; ++kb) hfr[kb] = *(const f16x8*)(hp + kb * 32);
      f32x4 a = {0.f, 0.f, 0.f, 0.f};
      #pragma unroll
      for (int kb = 0; kb < 8; ++kb)
        a = __builtin_amdgcn_mfma_f32_16x16x32_f16(hfr[kb], Bf[kb], a, 0, 0, 0);
      *(f32x4*)&ctile[3][lane][0] = a;
    } else if (wid == 4 || wid == 5) {
      f16x8 hfr[8];
      #pragma unroll
      for (int kb = 0; kb < 8; ++kb) hfr[kb] = *(const f16x8*)(hp + kb * 32);
      #pragma unroll
      for (int kb = 0; kb < 8; ++kb)
        acc45 = __builtin_amdgcn_mfma_f32_16x16x32_f16(hfr[kb], Bf[kb], acc45, 0, 0, 0);
    } else if (wid == 6) {
      f16x8 hfr[8];
      #pragma unroll
      for (int kb = 0; kb < 8; ++kb) hfr[kb] = *(const f16x8*)(hp + kb * 32);
      f32x4 a = {0.f, 0.f, 0.f, 0.f};
      #pragma unroll
      for (int kb = 0; kb < 8; ++kb)
        a = __builtin_amdgcn_mfma_f32_16x16x32_f16(hfr[kb], Bf[kb], a, 0, 0, 0);
      *(f32x4*)&ctile[6][lane][0] = a;
    }
    // wid7: no pre-barrier MFMA

    // (3.5) stage x[p+1]
    if (p + 1 < NS) {
      #pragma unroll
      for (int i = 0; i < 3; ++i)
        if (xv_[i]) xs[((p + 1) & 1) * (16 * XSS) + xr_[i] * XSS + xc_[i]] =
            (_Float16)xf[i];
    }
    bar_lds();   // S1: ct0..3,ct6 ready; hcat/xs(par) reads done

    // (4) CONCURRENT: half0 = L0 gates + publish h0[p]; half1 = validate h1[p-2]
    const int li = ((row >> 2) << 4) | u, rg = row & 3;
    if (tid < 256) {
      if (p < NS) {
        const float ar = ctile[0][li][rg] + gbr;
        const float az = ctile[1][li][rg] + gbz;
        const float nx = ctile[2][li][rg] + gbnx;
        const float nh = ctile[3][li][rg] + gbnh;
        const float r = 1.f / (1.f + __expf(-ar));
        const float z = 1.f / (1.f + __expf(-az));
        const float n = tanhf(nx + r * nh);
        h0f = (1.f - z) * n + z * h0f;
        union { _Float16 h; unsigned short s; } c; c.h = (_Float16)h0f;
        st_u32_sys(hx0 + par * 65536 + gr * 4096 + row * 256 + gu,
                   (unsigned)c.s | ((unsigned)(p + 1) << 16));
      }
    } else {
      if (p >= 2) {
        asm volatile("s_waitcnt vmcnt(0)"
                     : "+v"(G0), "+v"(G1), "+v"(G2), "+v"(G3) :: "memory");
        while (!tags_ok(G0, G1, G2, G3, (unsigned)(p - 1))) {
          if (++spins > 200000) { dead = 1; break; }
          __builtin_amdgcn_s_sleep(1);
          ld4b_sys(hx1 + par * 65536 + chunk, G0, G1, G2, G3);
        }
        unpack16(hcat + row * HCS + 256 + u * 16, G0, G1, G2, G3);
      }
    }
    bar_lds();   // S2: h1[p-2] in hcat; h0[p] published

    // (6) half0: async h0[p] gather; waves 4/5/7: h1-part MFMAs
    u32x4 A0, A1, A2, A3;
    if (tid < 256 && p < NS)
      issue4_sys(hx0 + par * 65536 + chunk, A0, A1, A2, A3);
    if (wid == 4 || wid == 5) {
      const _Float16* hq = hcat + lrow * HCS + 256 + lko;
      f16x8 h1r[8];
      #pragma unroll
      for (int kb = 0; kb < 8; ++kb) h1r[kb] = *(const f16x8*)(hq + kb * 32);
      #pragma unroll
      for (int kb = 0; kb < 8; ++kb)
        acc45 = __builtin_amdgcn_mfma_f32_16x16x32_f16(h1r[kb], Bf[8 + kb], acc45, 0, 0, 0);
      *(f32x4*)&ctile[wid][lane][0] = acc45;
    } else if (wid == 7) {
      const _Float16* hq = hcat + lrow * HCS + 256 + lko;
      f16x8 h1r[8];
      #pragma unroll
      for (int kb = 0; kb < 8; ++kb) h1r[kb] = *(const f16x8*)(hq + kb * 32);
      f32x4 a = {0.f, 0.f, 0.f, 0.f};
      #pragma unroll
      for (int kb = 0; kb < 8; ++kb)
        a = __builtin_amdgcn_mfma_f32_16x16x32_f16(h1r[kb], Bf[kb], a, 0, 0, 0);
      *(f32x4*)&ctile[7][lane][0] = a;
    }
    bar_lds();   // S3: ct4..7 ready

    // (7)/(8) CONCURRENT: half1 = L1 gates + publish h1[p-1]; half0 = validate h0[p]
    if (tid >= 256) {
      if (p >= 1) {
        const float ar = ctile[4][li][rg] + gbr;
        const float az = ctile[5][li][rg] + gbz;
        const float nx = ctile[6][li][rg] + gbnx;
        const float nh = ctile[7][li][rg] + gbnh;
        const float r = 1.f / (1.f + __expf(-ar));
        const float z = 1.f / (1.f + __expf(-az));
        const float n = tanhf(nx + r * nh);
        h1f = (1.f - z) * n + z * h1f;
        union { _Float16 h; unsigned short s; } c; c.h = (_Float16)h1f;
        st_u32_sys(hx1 + ((p - 1) & 1) * 65536 + gr * 4096 + row * 256 + gu,
                   (unsigned)c.s | ((unsigned)p << 16));
      }
    } else {
      if (p < NS) {
        asm volatile("s_waitcnt vmcnt(0)"
                     : "+v"(A0), "+v"(A1), "+v"(A2), "+v"(A3) :: "memory");
        while (!tags_ok(A0, A1, A2, A3, (unsigned)(p + 1))) {
          if (++spins > 200000) { dead = 1; break; }
          __builtin_amdgcn_s_sleep(1);
          ld4b_sys(hx0 + par * 65536 + chunk, A0, A1, A2, A3);
        }
        unpack16(hcat + row * HCS + u * 16, A0, A1, A2, A3);
      }
    }
    bar_lds();   // S4
  }

  // ---- final: half1 gathers h1[NS-1] (slot (NS-1)&1, tag NS) ----
  if (tid >= 256) {
    u32x4 C0, C1, C2, C3;
    const unsigned* src = hx1 + ((NS - 1) & 1) * 65536 + chunk;
    for (;;) {
      ld4b_sys(src, C0, C1, C2, C3);
      if (tags_ok(C0, C1, C2, C3, (unsigned)NS)) break;
      if (++spins > 200000) { dead = 1; break; }
      __builtin_amdgcn_s_sleep(1);
    }
    unpack16(hcat + row * HCS + 256 + u * 16, C0, C1, C2, C3);
  }
  __syncthreads();
  if (tid < 256) {
    float part = 0.f;
    #pragma unroll
    for (int e = 0; e < 16; ++e)
      part += (float)hcat[row * HCS + 256 + u * 16 + e] * w_lin[u * 16 + e];
    red[row][u] = part;
  }
  __syncthreads();
  if (j == 0 && tid < 16) {
    float s = 0.f;
    #pragma unroll
    for (int e = 0; e < 16; ++e) s += red[tid][e];
    out[gr * 16 + tid] = s + b_lin[0];
  }
}

extern "C" void kernel_launch(void* const* d_in, const int* in_sizes, int n_in,
                              void* d_out, int out_size, void* d_ws, size_t ws_size,
                              hipStream_t stream) {
  (void)in_sizes; (void)n_in; (void)out_size; (void)ws_size;
  const float* x     = (const float*)d_in[0];
  const float* w_ih0 = (const float*)d_in[1];
  const float* w_hh0 = (const float*)d_in[2];
  const float* b_ih0 = (const float*)d_in[3];
  const float* b_hh0 = (const float*)d_in[4];
  const float* w_ih1 = (const float*)d_in[5];
  const float* w_hh1 = (const float*)d_in[6];
  const float* b_ih1 = (const float*)d_in[7];
  const float* b_hh1 = (const float*)d_in[8];
  const float* w_lin = (const float*)d_in[9];
  const float* b_lin = (const float*)d_in[10];

  char* ws = (char*)d_ws;
  _Float16* wimg = (_Float16*)(ws + WIMG_OFF);
  unsigned* hx0  = (unsigned*)(ws + HX0_OFF);
  unsigned* hx1  = (unsigned*)(ws + HX1_OFF);

  hipMemsetAsync(ws + HX0_OFF, 0, HX_TOTAL_BYTES, stream);
  prep_wimg<<<1024, 256, 0, stream>>>(w_ih0, w_hh0, w_ih1, w_hh1, wimg);
  gru_mfma<<<256, 512, 0, stream>>>(x, b_ih0, b_hh0, b_ih1, b_hh1,
                                    w_lin, b_lin, wimg, hx0, hx1,
                                    (float*)d_out);
}